// Round 9
// baseline (211.539 us; speedup 1.0000x reference)
//
#include <hip/hip_runtime.h>

// Problem constants (fixed by setup_inputs)
constexpr int B = 4;
constexpr int C = 64;    // input channels
constexpr int O = 64;    // output channels (main conv)
constexpr int OOFF = 18; // offset channels = 2*3*3
constexpr int H = 192;
constexpr int W = 192;

typedef __attribute__((ext_vector_type(8))) short short8;   // 8 bf16 = 4 VGPR
typedef __attribute__((ext_vector_type(4))) float float4v;  // MFMA acc
typedef __attribute__((ext_vector_type(2))) float f32x2;    // v_pk_fma_f32 pair
typedef __attribute__((ext_vector_type(2))) uint u32x2;
typedef __attribute__((ext_vector_type(2))) __bf16 bf16x2;

__device__ inline ushort f2bf(float f) { // RNE via HW __bf16 convert
  return __builtin_bit_cast(ushort, (__bf16)f);
}
__device__ inline uint pk2bf(float lo, float hi) { // pack 2 bf16 (RNE)
  bf16x2 v;
  v.x = (__bf16)lo;
  v.y = (__bf16)hi;
  return __builtin_bit_cast(uint, v);
}
__device__ inline f32x2 upk(uint u) { // unpack 2 bf16 -> 2 f32
  u32x2 t;
  t.x = u << 16;
  t.y = u & 0xffff0000u;
  return __builtin_bit_cast(f32x2, t);
}

// -------------------------------------------------------------------------
// Kernel PRE (fused): blocks [0,9216): transpose x fp32 NCHW -> xtb bf16
// channels-last. [9216,9360): w_conv -> wBf (PERMUTED n-map oc = nt+4*col).
// [9360,9432): w_off -> wOf (plain n-map, N padded 18->32).
// -------------------------------------------------------------------------
__global__ __launch_bounds__(256) void k_pre(const float* __restrict__ x,
                                             ushort* __restrict__ xtb,
                                             const float* __restrict__ w_conv,
                                             ushort* __restrict__ wBf,
                                             const float* __restrict__ w_off,
                                             ushort* __restrict__ wOf) {
  __shared__ float tile[64][17];
  const int bid = blockIdx.x;
  const int tid = threadIdx.x;
  if (bid < 9216) { // transpose
    const int w0 = (bid % 12) * 16;
    const int h = (bid / 12) % 192;
    const int b = bid / 2304;
    const int wl = tid & 15;
    const int c0 = tid >> 4;
#pragma unroll
    for (int r = 0; r < 4; ++r) {
      const int c = c0 + r * 16;
      tile[c][wl] = x[(((size_t)b * C + c) * H + h) * W + w0 + wl];
    }
    __syncthreads();
    const int c = tid & 63;
    const int qq = tid >> 6;
#pragma unroll
    for (int r = 0; r < 4; ++r) {
      const int wq = qq + r * 4;
      xtb[(((size_t)b * H + h) * W + w0 + wq) * C + c] = f2bf(tile[c][wq]);
    }
  } else if (bid < 9360) { // wBf: 36864 entries
    const int i = (bid - 9216) * 256 + tid;
    const int j = i & 7;
    const int lane = (i >> 3) & 63;
    const int nt = (i >> 9) & 3;
    const int kstep = (i >> 11) & 1;
    const int kk = i >> 12;
    const int n = nt + 4 * (lane & 15); // permuted
    const int c = kstep * 32 + ((lane >> 4) & 3) * 8 + j;
    wBf[i] = f2bf(w_conv[((size_t)n * C + c) * 9 + kk]);
  } else { // wOf: 18432 entries
    const int i = (bid - 9360) * 256 + tid;
    const int j = i & 7;
    const int lane = (i >> 3) & 63;
    const int nt = (i >> 9) & 1;
    const int ks = (i >> 10) & 1;
    const int kk = i >> 11;
    const int n = nt * 16 + (lane & 15);
    const int c = ks * 32 + ((lane >> 4) & 3) * 8 + j;
    wOf[i] = (n < OOFF) ? f2bf(w_off[((size_t)n * C + c) * 9 + kk]) : (ushort)0;
  }
}

// -------------------------------------------------------------------------
// Kernel OFFS: standalone offset conv (M=147456, N=18, K=576) via MFMA.
// Split out of k_fused so (a) the weight reads amortize over M=64 px/wave
// (4x fewer wOf/A load insts than in-fused M=16) and (b) the deform kernel
// becomes visible/simple. Phase-1 structure copied from the verified r5
// kernel (passed absmax 0.03125). Output: offp[(b,h,w)][oc pad20] f32
// (+bias), exact f32 round-trip -> bit-identical downstream math.
// grid 576 x 256 thr; each wave owns one 8x8 tile (same XCD-swizzled map).
// -------------------------------------------------------------------------
__global__ __launch_bounds__(256) void k_offs(const ushort* __restrict__ xtb,
                                              const ushort* __restrict__ wOf,
                                              const float* __restrict__ b_off,
                                              float* __restrict__ offp) {
  const int tile = blockIdx.x * 4 + (threadIdx.x >> 6); // 0..2303
  const int lane = threadIdx.x & 63;
  const int xcd = tile & 7;
  const int s0 = tile >> 3; // 0..287
  const int b = xcd >> 1;
  const int half = xcd & 1;
  const int th = s0 / 24; // 0..11
  const int tw = s0 % 24; // 0..23
  const int h0 = half * 96 + th * 8, w0 = tw * 8;
  const int col = lane & 15, quad = lane >> 4;

  float4v oacc[4][2]; // [mt][nt]
#pragma unroll
  for (int mt = 0; mt < 4; ++mt)
#pragma unroll
    for (int nt = 0; nt < 2; ++nt) oacc[mt][nt] = (float4v){0.f, 0.f, 0.f, 0.f};

  short8 oafr[2][4][2]; // [pb][mt][ks] A fragments, double-buffered

  auto oload = [&](int kk, int pb) {
    const int ky = kk / 3, kx = kk % 3;
    const int ww = w0 + (col & 7) + kx - 1;
    const bool wok = (unsigned)ww < (unsigned)W;
    const int wwc = min(max(ww, 0), W - 1);
#pragma unroll
    for (int mt = 0; mt < 4; ++mt) {
      const int hh = h0 + 2 * mt + (col >> 3) + ky - 1;
      const bool ok = wok && ((unsigned)hh < (unsigned)H);
      const int hhc = min(max(hh, 0), H - 1);
      const ushort* pa = xtb + (((size_t)b * H + hhc) * W + wwc) * C + quad * 8;
#pragma unroll
      for (int ks = 0; ks < 2; ++ks) {
        short8 v = (short8)0;
        if (ok) v = *(const short8*)(pa + ks * 32);
        oafr[pb][mt][ks] = v;
      }
    }
  };

  oload(0, 0);
#pragma unroll 2 // pb = kk&1 stays compile-time
  for (int kk = 0; kk < 9; ++kk) {
    const int pb = kk & 1;
    if (kk < 8) oload(kk + 1, pb ^ 1);
#pragma unroll
    for (int ks = 0; ks < 2; ++ks)
#pragma unroll
      for (int nt = 0; nt < 2; ++nt) {
        const short8 bw = *(const short8*)&wOf[((((size_t)kk * 2 + ks) * 2 + nt) * 64 + lane) * 8];
#pragma unroll
        for (int mt = 0; mt < 4; ++mt) // bw reused 4x
          oacc[mt][nt] =
              __builtin_amdgcn_mfma_f32_16x16x32_bf16(oafr[pb][mt][ks], bw, oacc[mt][nt], 0, 0, 0);
      }
  }

  // write offsets (+bias) to offp rows [px][20]
#pragma unroll
  for (int nt = 0; nt < 2; ++nt) {
    const int oc = nt * 16 + col;
    if (oc < OOFF) {
      const float bias = b_off[oc];
#pragma unroll
      for (int mt = 0; mt < 4; ++mt)
#pragma unroll
        for (int r = 0; r < 4; ++r) {
          const int px = mt * 16 + quad * 4 + r; // pixel in 8x8 tile
          const int hh = h0 + (px >> 3), ww = w0 + (px & 7);
          offp[(((size_t)b * H + hh) * W + ww) * 20 + oc] = oacc[mt][nt][r] + bias;
        }
    }
  }
}

// -------------------------------------------------------------------------
// Kernel DEFORM: r4's phase 2 verbatim (best measured structure: 76.5us as
// part of k_fused across 8 variants), with phase 1 replaced by a 20-register
// offset preamble (one coalesced 80B read per pixel, exact f32). No offBuf,
// no setprio (r8: setprio cost 7-10us). sA exchange + (p,qtr) gather lane
// mapping kept exactly (r7: reordering lanes costs 62% via coalescing loss).
// grid 4608 x 128 thr (2 decoupled waves), XCD swizzle.
// -------------------------------------------------------------------------
__global__ __launch_bounds__(128) void k_deform(
    const ushort* __restrict__ xtb, const float* __restrict__ offp,
    const ushort* __restrict__ wBf, const float* __restrict__ b_conv,
    ushort* __restrict__ yt) {
  __shared__ ushort sA[2][2][64][8]; // [wave][ks][row][j] = 4 KB

  const int bid = blockIdx.x;
  const int xcd = bid & 7;
  const int s0 = bid >> 3; // 0..575
  const int b = xcd >> 1;
  const int half = xcd & 1;
  const int th = s0 / 24; // 0..23
  const int tw = s0 % 24; // 0..23

  const int tid = threadIdx.x;
  const int wave = tid >> 6, lane = tid & 63;
  const int h0 = half * 96 + th * 4 + wave * 2; // this wave's 2-row band
  const int w0 = tw * 8;

  const int col = lane & 15, quad = lane >> 4;
  const int p = lane >> 2, qtr = lane & 3; // pixel 0..15, channel-quarter
  const int ph = h0 + (p >> 3), pw = w0 + (p & 7); // this thread's gather pixel

  // ---- offset preamble: 80B coalesced read -> 18 useful floats in regs ----
  const float* orow = offp + (((size_t)b * H + ph) * W + pw) * 20;
  const float4 v0 = *(const float4*)(orow + 0);
  const float4 v1 = *(const float4*)(orow + 4);
  const float4 v2 = *(const float4*)(orow + 8);
  const float4 v3 = *(const float4*)(orow + 12);
  const float2 v4 = *(const float2*)(orow + 16);
  float oy[9], ox[9]; // indexed only by compile-time kk (full unroll below)
  oy[0] = v0.x; ox[0] = v0.y; oy[1] = v0.z; ox[1] = v0.w;
  oy[2] = v1.x; ox[2] = v1.y; oy[3] = v1.z; ox[3] = v1.w;
  oy[4] = v2.x; ox[4] = v2.y; oy[5] = v2.z; ox[5] = v2.w;
  oy[6] = v3.x; ox[6] = v3.y; oy[7] = v3.z; ox[7] = v3.w;
  oy[8] = v4.x; ox[8] = v4.y;

  // ===================== deformable conv phase (r4 verbatim) ================
  const ushort* xbase = xtb + (size_t)b * H * W * C;
  const uint qoff = (uint)qtr * 16u; // 16B slice within line 0 of the pixel
  const float hm1 = (float)(ph - 1), wm1 = (float)(pw - 1);

  uint offs[4];       // single-slot corner byte offsets (next kk to load)
  float4 awv;         // single-slot bilinear weights (current kk to blend)
  uint4 gA[4], gB[4]; // both chunks in flight a full kk ahead (32 VGPR)

  auto calc = [&](int kk) {
    const int ky = kk / 3, kx = kk % 3;
    const float pyf = oy[kk] + hm1 + (float)ky;
    const float pxf = ox[kk] + wm1 + (float)kx;
    const float fy0 = floorf(pyf), fx0 = floorf(pxf);
    const float wy = pyf - fy0, wx = pxf - fx0;
    const int iy0 = (int)fy0, ix0 = (int)fx0;
    const int iy1 = iy0 + 1, ix1 = ix0 + 1;
    const bool vy0 = (unsigned)iy0 < (unsigned)H;
    const bool vy1 = (unsigned)iy1 < (unsigned)H;
    const bool vx0 = (unsigned)ix0 < (unsigned)W;
    const bool vx1 = (unsigned)ix1 < (unsigned)W;
    awv.x = (vy0 && vx0) ? (1.f - wy) * (1.f - wx) : 0.f;
    awv.y = (vy0 && vx1) ? (1.f - wy) * wx : 0.f;
    awv.z = (vy1 && vx0) ? wy * (1.f - wx) : 0.f;
    awv.w = (vy1 && vx1) ? wy * wx : 0.f;
    const int cy0 = min(max(iy0, 0), H - 1), cy1 = min(max(iy1, 0), H - 1);
    const int cx0 = min(max(ix0, 0), W - 1), cx1 = min(max(ix1, 0), W - 1);
    offs[0] = (uint)((cy0 * W + cx0) * (C * 2)) + qoff;
    offs[1] = (uint)((cy0 * W + cx1) * (C * 2)) + qoff;
    offs[2] = (uint)((cy1 * W + cx0) * (C * 2)) + qoff;
    offs[3] = (uint)((cy1 * W + cx1) * (C * 2)) + qoff;
  };

  auto loadAB = [&]() {
#pragma unroll
    for (int c = 0; c < 4; ++c)
      gA[c] = *(const uint4*)((const char*)xbase + offs[c]); // line 0 (ch 8q..)
#pragma unroll
    for (int c = 0; c < 4; ++c)
      gB[c] = *(const uint4*)((const char*)xbase + offs[c] + 64u); // line 1
  };
  auto blend = [&](const uint4* g, uint* pk) {
    const f32x2 a00 = {awv.x, awv.x};
    const f32x2 a01 = {awv.y, awv.y};
    const f32x2 a10 = {awv.z, awv.z};
    const f32x2 a11 = {awv.w, awv.w};
#pragma unroll
    for (int i = 0; i < 4; ++i) {
      f32x2 sv = upk(g[0][i]) * a00 + upk(g[1][i]) * a01 + upk(g[2][i]) * a10 + upk(g[3][i]) * a11;
      pk[i] = pk2bf(sv.x, sv.y);
    }
  };

  float4v acc[4];
#pragma unroll
  for (int nt = 0; nt < 4; ++nt) acc[nt] = (float4v){0.f, 0.f, 0.f, 0.f};

  calc(0);
  loadAB(); // kk=0 fully in flight
#pragma unroll
  for (int kk = 0; kk < 9; ++kk) {
    uint pkA[4];
    blend(gA, pkA); // chunk A = channels 8*qtr..8*qtr+7 (ks=0, k-group qtr)
    *(uint4*)&sA[wave][0][p | (qtr << 4)][0] = *(const uint4*)pkA;
    uint pkB[4];
    blend(gB, pkB); // chunk B = channels 32+8*qtr.. (ks=1, k-group qtr)
    *(uint4*)&sA[wave][1][p | (qtr << 4)][0] = *(const uint4*)pkB;

    if (kk < 8) {
      calc(kk + 1); // safe: awv/offs consumed above (single slot)
      loadAB();     // next kk fully in flight, covered by MFMA below
    }

    // intra-wave exchange: writes above, reads below, same wave => ordered.
#pragma unroll
    for (int ks = 0; ks < 2; ++ks) {
      const short8 a = *(const short8*)&sA[wave][ks][lane][0];
#pragma unroll
      for (int nt = 0; nt < 4; ++nt) {
        const short8 bb = *(const short8*)&wBf[((((size_t)kk * 2 + ks) * 4 + nt) * 64 + lane) * 8];
        acc[nt] = __builtin_amdgcn_mfma_f32_16x16x32_bf16(a, bb, acc[nt], 0, 0, 0);
      }
    }
  }

  // epilogue: yt[b][h][w][c] bf16, oc = nt + 4*(lane&15) (permuted)
  float bias[4];
#pragma unroll
  for (int nt = 0; nt < 4; ++nt) bias[nt] = b_conv[4 * col + nt];
#pragma unroll
  for (int r = 0; r < 4; ++r) {
    const int pp = quad * 4 + r; // pixel index in this wave's 2x8 band
    const int hrow = h0 + (pp >> 3), wcol = w0 + (pp & 7);
    uint2 u;
    u.x = pk2bf(acc[0][r] + bias[0], acc[1][r] + bias[1]);
    u.y = pk2bf(acc[2][r] + bias[2], acc[3][r] + bias[3]);
    *(uint2*)&yt[((size_t)(b * H + hrow) * W + wcol) * C + 4 * col] = u;
  }
}

// -------------------------------------------------------------------------
// Kernel 4: main 3x3 conv via bf16 MFMA, LDS-free, 1-stage pipelined frags.
// Round-2 known-good shape (r8 proved B-buffering choice is neutral; keep
// the longest-tested variant): 256 threads, wave = 2 rows x 64 oc, B-frags
// register-double-buffered. grid (12, 24, 4) = 1152 blocks.
// -------------------------------------------------------------------------
__global__ __launch_bounds__(256) void k_conv_main_mfma(
    const ushort* __restrict__ yt, const ushort* __restrict__ wBf,
    const float* __restrict__ b_conv, float* __restrict__ out) {
  const int w0 = blockIdx.x * 16;
  const int b = blockIdx.z;
  const int tid = threadIdx.x;
  const int wave = tid >> 6, lane = tid & 63;
  const int col = lane & 15, quad = lane >> 4;
  const int h0 = blockIdx.y * 8 + wave * 2;

  float4v acc[2][4];
#pragma unroll
  for (int mt = 0; mt < 2; ++mt)
#pragma unroll
    for (int nt = 0; nt < 4; ++nt) acc[mt][nt] = (float4v){0.f, 0.f, 0.f, 0.f};

  short8 bfr[2][2][4]; // [pb][ks][nt]
  short8 afr[2][2][2]; // [pb][mt][ks]

  auto load = [&](int kk, int pb) {
    const int ky = kk / 3, kx = kk % 3;
    const int ww = w0 + col + kx - 1;
    const bool wok = (unsigned)ww < (unsigned)W;
    const int wwc = min(max(ww, 0), W - 1);
#pragma unroll
    for (int ks = 0; ks < 2; ++ks)
#pragma unroll
      for (int nt = 0; nt < 4; ++nt)
        bfr[pb][ks][nt] = *(const short8*)&wBf[((((size_t)kk * 2 + ks) * 4 + nt) * 64 + lane) * 8];
#pragma unroll
    for (int mt = 0; mt < 2; ++mt) {
      const int hh = h0 + mt + ky - 1;
      const bool ok = wok && ((unsigned)hh < (unsigned)H);
      const int hhc = min(max(hh, 0), H - 1);
      const ushort* pa = yt + (((size_t)b * H + hhc) * W + wwc) * C + quad * 8;
#pragma unroll
      for (int ks = 0; ks < 2; ++ks) {
        short8 v = (short8)0;
        if (ok) v = *(const short8*)(pa + ks * 32);
        afr[pb][mt][ks] = v;
      }
    }
  };

  load(0, 0);
#pragma unroll
  for (int kk = 0; kk < 9; ++kk) {
    const int pb = kk & 1;
    if (kk < 8) load(kk + 1, pb ^ 1);
#pragma unroll
    for (int ks = 0; ks < 2; ++ks)
#pragma unroll
      for (int mt = 0; mt < 2; ++mt)
#pragma unroll
        for (int nt = 0; nt < 4; ++nt)
          acc[mt][nt] = __builtin_amdgcn_mfma_f32_16x16x32_bf16(afr[pb][mt][ks], bfr[pb][ks][nt],
                                                                acc[mt][nt], 0, 0, 0);
  }

  float bias[4];
#pragma unroll
  for (int nt = 0; nt < 4; ++nt) bias[nt] = b_conv[4 * col + nt];
#pragma unroll
  for (int mt = 0; mt < 2; ++mt) {
    const int h = h0 + mt;
#pragma unroll
    for (int nt = 0; nt < 4; ++nt) {
      const int oc = 4 * col + nt; // permuted C/D col -> oc
      float4 v;
      v.x = acc[mt][nt][0] + bias[nt];
      v.y = acc[mt][nt][1] + bias[nt];
      v.z = acc[mt][nt][2] + bias[nt];
      v.w = acc[mt][nt][3] + bias[nt];
      *(float4*)&out[(((size_t)b * O + oc) * H + h) * W + w0 + quad * 4] = v;
    }
  }
}

// -------------------------------------------------------------------------
extern "C" void kernel_launch(void* const* d_in, const int* in_sizes, int n_in,
                              void* d_out, int out_size, void* d_ws, size_t ws_size,
                              hipStream_t stream) {
  const float* x = (const float*)d_in[0];
  const float* w_off = (const float*)d_in[1];
  const float* b_off = (const float*)d_in[2];
  const float* w_conv = (const float*)d_in[3];
  const float* b_conv = (const float*)d_in[4];
  float* out = (float*)d_out;

  ushort* xtb = (ushort*)d_ws;              // B*H*W*C bf16           (18.87 MB)
  ushort* yt = xtb + (size_t)B * H * W * C; // B*H*W*C bf16           (18.87 MB)
  ushort* wBf = yt + (size_t)B * H * W * C; // 36864 bf16
  ushort* wOf = wBf + 36864;                // 18432 bf16
  float* offp = (float*)(wOf + 18432);      // B*H*W*20 f32 offsets   (11.80 MB)

  k_pre<<<dim3(9432), dim3(256), 0, stream>>>(x, xtb, w_conv, wBf, w_off, wOf);
  k_offs<<<dim3(576), dim3(256), 0, stream>>>(xtb, wOf, b_off, offp);
  k_deform<<<dim3(4608), dim3(128), 0, stream>>>(xtb, offp, wBf, b_conv, yt);
  k_conv_main_mfma<<<dim3(W / 16, H / 8, B), dim3(256), 0, stream>>>(yt, wBf, b_conv, out);
}

// Round 10
// 198.321 us; speedup vs baseline: 1.0666x; 1.0666x over previous
//
#include <hip/hip_runtime.h>

// Problem constants (fixed by setup_inputs)
constexpr int B = 4;
constexpr int C = 64;    // input channels
constexpr int O = 64;    // output channels (main conv)
constexpr int OOFF = 18; // offset channels = 2*3*3
constexpr int H = 192;
constexpr int W = 192;

typedef __attribute__((ext_vector_type(8))) short short8;   // 8 bf16 = 4 VGPR
typedef __attribute__((ext_vector_type(4))) float float4v;  // MFMA acc
typedef __attribute__((ext_vector_type(2))) float f32x2;    // v_pk_fma_f32 pair
typedef __attribute__((ext_vector_type(2))) uint u32x2;
typedef __attribute__((ext_vector_type(2))) __bf16 bf16x2;

__device__ inline ushort f2bf(float f) { // RNE via HW __bf16 convert
  return __builtin_bit_cast(ushort, (__bf16)f);
}
__device__ inline uint pk2bf(float lo, float hi) { // pack 2 bf16 (RNE)
  bf16x2 v;
  v.x = (__bf16)lo;
  v.y = (__bf16)hi;
  return __builtin_bit_cast(uint, v);
}
__device__ inline f32x2 upk(uint u) { // unpack 2 bf16 -> 2 f32
  u32x2 t;
  t.x = u << 16;
  t.y = u & 0xffff0000u;
  return __builtin_bit_cast(f32x2, t);
}

// -------------------------------------------------------------------------
// Kernel PRE v2. Old version: 9216 micro-blocks (4 KB in each), SCALAR dword
// loads + scalar 2B bf16 stores -> inferred ~50us (r9 bounds: every non-
// k_deform kernel <53.4us yet pre+conv+OH=123us). THIS REV: 2304 transpose
// blocks, each 4 h-rows x 16 w x 64 c (16 KB in / 8 KB out), float4 global
// loads (16B/lane; 64B contiguous per 4-lane c-row group), LDS [4][64][17]
// f32 (pad 17 kills bank conflicts), packed uint2 bf16 stores (128B per
// 16-lane group). Same per-element RNE convert + same mapping as before ->
// bit-identical xtb. Blocks [2304,2448): wBf prep; [2448,2520): wOf prep
// (unchanged math, rebased block ids).
// -------------------------------------------------------------------------
__global__ __launch_bounds__(256) void k_pre(const float* __restrict__ x,
                                             ushort* __restrict__ xtb,
                                             const float* __restrict__ w_conv,
                                             ushort* __restrict__ wBf,
                                             const float* __restrict__ w_off,
                                             ushort* __restrict__ wOf) {
  __shared__ float tile[4][64][17];
  const int bid = blockIdx.x;
  const int tid = threadIdx.x;
  if (bid < 2304) { // transpose: b = bid/576, h0 = ((bid/12)%48)*4, w0 = (bid%12)*16
    const int w0 = (bid % 12) * 16;
    const int h0 = ((bid / 12) % 48) * 4;
    const int b = bid / 576;
    const int c = tid >> 2, wq4 = tid & 3; // 64 c x 4 float4-slots covers 16 w
#pragma unroll
    for (int hr = 0; hr < 4; ++hr) {
      const float4 v =
          *(const float4*)&x[(((size_t)b * C + c) * H + h0 + hr) * W + w0 + wq4 * 4];
      tile[hr][c][wq4 * 4 + 0] = v.x;
      tile[hr][c][wq4 * 4 + 1] = v.y;
      tile[hr][c][wq4 * 4 + 2] = v.z;
      tile[hr][c][wq4 * 4 + 3] = v.w;
    }
    __syncthreads();
    const int cq = tid & 15, wq = tid >> 4; // 16 c-quads x 16 w
#pragma unroll
    for (int hr = 0; hr < 4; ++hr) {
      uint2 u;
      u.x = pk2bf(tile[hr][cq * 4 + 0][wq], tile[hr][cq * 4 + 1][wq]);
      u.y = pk2bf(tile[hr][cq * 4 + 2][wq], tile[hr][cq * 4 + 3][wq]);
      *(uint2*)&xtb[(((size_t)b * H + h0 + hr) * W + w0 + wq) * C + cq * 4] = u;
    }
  } else if (bid < 2448) { // wBf: 36864 entries (144 blocks)
    const int i = (bid - 2304) * 256 + tid;
    const int j = i & 7;
    const int lane = (i >> 3) & 63;
    const int nt = (i >> 9) & 3;
    const int kstep = (i >> 11) & 1;
    const int kk = i >> 12;
    const int n = nt + 4 * (lane & 15); // permuted
    const int c = kstep * 32 + ((lane >> 4) & 3) * 8 + j;
    wBf[i] = f2bf(w_conv[((size_t)n * C + c) * 9 + kk]);
  } else { // wOf: 18432 entries (72 blocks)
    const int i = (bid - 2448) * 256 + tid;
    const int j = i & 7;
    const int lane = (i >> 3) & 63;
    const int nt = (i >> 9) & 1;
    const int ks = (i >> 10) & 1;
    const int kk = i >> 11;
    const int n = nt * 16 + (lane & 15);
    const int c = ks * 32 + ((lane >> 4) & 3) * 8 + j;
    wOf[i] = (n < OOFF) ? f2bf(w_off[((size_t)n * C + c) * 9 + kk]) : (ushort)0;
  }
}

// -------------------------------------------------------------------------
// Kernel FUSED: best-measured variant, restored VERBATIM (76.6us @ round-4
// bench; the r9 split into k_offs+k_deform cost a net ~12us — standalone
// offset conv + offp round-trip is pricier than fused phase-1). 2-wave
// (128-thread) blocks, grid 4608; waves fully decoupled (per-wave LDS slabs,
// no __syncthreads). Gather lane map (p=lane>>2, qtr=lane&3) preserved (r7:
// reordering costs 62% via coalescing loss). Chunk A = line 0 (bytes
// qtr*16), chunk B = line 1 (+64B). No setprio (r8: cost 7-10us).
// -------------------------------------------------------------------------
__global__ __launch_bounds__(128) void k_fused(
    const ushort* __restrict__ xtb, const ushort* __restrict__ wOf,
    const float* __restrict__ b_off, const ushort* __restrict__ wBf,
    const float* __restrict__ b_conv, ushort* __restrict__ yt) {
  __shared__ ushort sA[2][2][64][8];                // [wave][ks][row][j] = 4 KB
  __shared__ __align__(16) float offBuf[2][16][20]; // [wave][pl][oc(18,pad20)] = 2.5 KB

  const int bid = blockIdx.x;
  const int xcd = bid & 7;
  const int s0 = bid >> 3; // 0..575
  const int b = xcd >> 1;
  const int half = xcd & 1;
  const int th = s0 / 24; // 0..23
  const int tw = s0 % 24; // 0..23

  const int tid = threadIdx.x;
  const int wave = tid >> 6, lane = tid & 63;
  const int h0 = half * 96 + th * 4 + wave * 2; // this wave's 2-row band
  const int w0 = tw * 8;

  const int col = lane & 15, quad = lane >> 4;
  const int p = lane >> 2, qtr = lane & 3; // pixel 0..15, channel-quarter
  const int prow = p >> 3, pcol = p & 7;
  const int h = h0 + prow, w = w0 + pcol;

  // ===================== Phase 1: offset conv (per wave) =====================
  {
    float4v oacc[2];
#pragma unroll
    for (int nt = 0; nt < 2; ++nt) oacc[nt] = (float4v){0.f, 0.f, 0.f, 0.f};

    short8 oafr[2][2]; // [pb][ks] — A fragments double-buffered; weights inline

    auto oload = [&](int kk, int pb) {
      const int ky = kk / 3, kx = kk % 3;
      const int hh = h0 + (col >> 3) + ky - 1;
      const int ww = w0 + (col & 7) + kx - 1;
      const bool ok = ((unsigned)hh < (unsigned)H) && ((unsigned)ww < (unsigned)W);
      const int hhc = min(max(hh, 0), H - 1);
      const int wwc = min(max(ww, 0), W - 1);
      const ushort* pa = xtb + (((size_t)b * H + hhc) * W + wwc) * C + quad * 8;
#pragma unroll
      for (int ks = 0; ks < 2; ++ks) {
        short8 v = (short8)0;
        if (ok) v = *(const short8*)(pa + ks * 32);
        oafr[pb][ks] = v;
      }
    };

    oload(0, 0);
#pragma unroll 2 // keeps pb = kk&1 compile-time
    for (int kk = 0; kk < 9; ++kk) {
      const int pb = kk & 1;
      if (kk < 8) oload(kk + 1, pb ^ 1);
#pragma unroll
      for (int ks = 0; ks < 2; ++ks)
#pragma unroll
        for (int nt = 0; nt < 2; ++nt) {
          const short8 bw =
              *(const short8*)&wOf[((((size_t)kk * 2 + ks) * 2 + nt) * 64 + lane) * 8];
          oacc[nt] = __builtin_amdgcn_mfma_f32_16x16x32_bf16(oafr[pb][ks], bw, oacc[nt], 0, 0, 0);
        }
    }

    // distribute offsets: D[m=quad*4+r][n=nt*16+col] -> offBuf[wave][m][oc]
#pragma unroll
    for (int nt = 0; nt < 2; ++nt) {
      const int oc = nt * 16 + col;
      if (oc < OOFF) {
        const float bias = b_off[oc];
#pragma unroll
        for (int r = 0; r < 4; ++r)
          offBuf[wave][quad * 4 + r][oc] = oacc[nt][r] + bias;
      }
    }
  } // intra-wave LDS exchange: no barrier needed (same-wave ds ordering)

  // ===================== Phase 2: deformable conv =====================
  const ushort* xbase = xtb + (size_t)b * H * W * C;
  const uint qoff = (uint)qtr * 16u; // 16B slice within line 0 of the pixel
  const float hm1 = (float)(h - 1), wm1 = (float)(w - 1);

  uint offs[4];       // single-slot corner byte offsets (next kk to load)
  float4 awv;         // single-slot bilinear weights (current kk to blend)
  uint4 gA[4], gB[4]; // both chunks in flight a full kk ahead (32 VGPR)

  auto calc = [&](int kk) {
    const float2 ov = *(const float2*)&offBuf[wave][p][2 * kk];
    const int ky = kk / 3, kx = kk % 3;
    const float pyf = ov.x + hm1 + (float)ky;
    const float pxf = ov.y + wm1 + (float)kx;
    const float fy0 = floorf(pyf), fx0 = floorf(pxf);
    const float wy = pyf - fy0, wx = pxf - fx0;
    const int iy0 = (int)fy0, ix0 = (int)fx0;
    const int iy1 = iy0 + 1, ix1 = ix0 + 1;
    const bool vy0 = (unsigned)iy0 < (unsigned)H;
    const bool vy1 = (unsigned)iy1 < (unsigned)H;
    const bool vx0 = (unsigned)ix0 < (unsigned)W;
    const bool vx1 = (unsigned)ix1 < (unsigned)W;
    awv.x = (vy0 && vx0) ? (1.f - wy) * (1.f - wx) : 0.f;
    awv.y = (vy0 && vx1) ? (1.f - wy) * wx : 0.f;
    awv.z = (vy1 && vx0) ? wy * (1.f - wx) : 0.f;
    awv.w = (vy1 && vx1) ? wy * wx : 0.f;
    const int cy0 = min(max(iy0, 0), H - 1), cy1 = min(max(iy1, 0), H - 1);
    const int cx0 = min(max(ix0, 0), W - 1), cx1 = min(max(ix1, 0), W - 1);
    offs[0] = (uint)((cy0 * W + cx0) * (C * 2)) + qoff;
    offs[1] = (uint)((cy0 * W + cx1) * (C * 2)) + qoff;
    offs[2] = (uint)((cy1 * W + cx0) * (C * 2)) + qoff;
    offs[3] = (uint)((cy1 * W + cx1) * (C * 2)) + qoff;
  };

  auto loadAB = [&]() {
#pragma unroll
    for (int c = 0; c < 4; ++c)
      gA[c] = *(const uint4*)((const char*)xbase + offs[c]); // line 0 (ch 8q..)
#pragma unroll
    for (int c = 0; c < 4; ++c)
      gB[c] = *(const uint4*)((const char*)xbase + offs[c] + 64u); // line 1
  };
  auto blend = [&](const uint4* g, uint* pk) {
    const f32x2 a00 = {awv.x, awv.x};
    const f32x2 a01 = {awv.y, awv.y};
    const f32x2 a10 = {awv.z, awv.z};
    const f32x2 a11 = {awv.w, awv.w};
#pragma unroll
    for (int i = 0; i < 4; ++i) {
      f32x2 sv = upk(g[0][i]) * a00 + upk(g[1][i]) * a01 + upk(g[2][i]) * a10 + upk(g[3][i]) * a11;
      pk[i] = pk2bf(sv.x, sv.y);
    }
  };

  float4v acc[4];
#pragma unroll
  for (int nt = 0; nt < 4; ++nt) acc[nt] = (float4v){0.f, 0.f, 0.f, 0.f};

  calc(0);
  loadAB(); // kk=0 fully in flight
#pragma unroll
  for (int kk = 0; kk < 9; ++kk) {
    uint pkA[4];
    blend(gA, pkA); // chunk A = channels 8*qtr..8*qtr+7 (ks=0, k-group qtr)
    *(uint4*)&sA[wave][0][p | (qtr << 4)][0] = *(const uint4*)pkA;
    uint pkB[4];
    blend(gB, pkB); // chunk B = channels 32+8*qtr.. (ks=1, k-group qtr)
    *(uint4*)&sA[wave][1][p | (qtr << 4)][0] = *(const uint4*)pkB;

    if (kk < 8) {
      calc(kk + 1); // safe: awv/offs consumed above (single slot)
      loadAB();     // next kk fully in flight, covered by MFMA below
    }

    // intra-wave exchange: writes above, reads below, same wave => ordered.
#pragma unroll
    for (int ks = 0; ks < 2; ++ks) {
      const short8 a = *(const short8*)&sA[wave][ks][lane][0];
#pragma unroll
      for (int nt = 0; nt < 4; ++nt) {
        const short8 bb = *(const short8*)&wBf[((((size_t)kk * 2 + ks) * 4 + nt) * 64 + lane) * 8];
        acc[nt] = __builtin_amdgcn_mfma_f32_16x16x32_bf16(a, bb, acc[nt], 0, 0, 0);
      }
    }
  }

  // epilogue: yt[b][h][w][c] bf16, oc = nt + 4*(lane&15) (permuted)
  float bias[4];
#pragma unroll
  for (int nt = 0; nt < 4; ++nt) bias[nt] = b_conv[4 * col + nt];
#pragma unroll
  for (int r = 0; r < 4; ++r) {
    const int pp = quad * 4 + r; // pixel index in this wave's 2x8 band
    const int hrow = h0 + (pp >> 3), wcol = w0 + (pp & 7);
    uint2 u;
    u.x = pk2bf(acc[0][r] + bias[0], acc[1][r] + bias[1]);
    u.y = pk2bf(acc[2][r] + bias[2], acc[3][r] + bias[3]);
    *(uint2*)&yt[((size_t)(b * H + hrow) * W + wcol) * C + 4 * col] = u;
  }
}

// -------------------------------------------------------------------------
// Kernel 4: main 3x3 conv via bf16 MFMA, LDS-free, 1-stage pipelined frags.
// Round-2 known-good shape, UNTOUCHED this round for clean attribution:
// 256 threads, wave = 2 rows x 64 oc, A+B register-double-buffered.
// grid (12, 24, 4) = 1152 blocks.
// -------------------------------------------------------------------------
__global__ __launch_bounds__(256) void k_conv_main_mfma(
    const ushort* __restrict__ yt, const ushort* __restrict__ wBf,
    const float* __restrict__ b_conv, float* __restrict__ out) {
  const int w0 = blockIdx.x * 16;
  const int b = blockIdx.z;
  const int tid = threadIdx.x;
  const int wave = tid >> 6, lane = tid & 63;
  const int col = lane & 15, quad = lane >> 4;
  const int h0 = blockIdx.y * 8 + wave * 2;

  float4v acc[2][4];
#pragma unroll
  for (int mt = 0; mt < 2; ++mt)
#pragma unroll
    for (int nt = 0; nt < 4; ++nt) acc[mt][nt] = (float4v){0.f, 0.f, 0.f, 0.f};

  short8 bfr[2][2][4]; // [pb][ks][nt]
  short8 afr[2][2][2]; // [pb][mt][ks]

  auto load = [&](int kk, int pb) {
    const int ky = kk / 3, kx = kk % 3;
    const int ww = w0 + col + kx - 1;
    const bool wok = (unsigned)ww < (unsigned)W;
    const int wwc = min(max(ww, 0), W - 1);
#pragma unroll
    for (int ks = 0; ks < 2; ++ks)
#pragma unroll
      for (int nt = 0; nt < 4; ++nt)
        bfr[pb][ks][nt] = *(const short8*)&wBf[((((size_t)kk * 2 + ks) * 4 + nt) * 64 + lane) * 8];
#pragma unroll
    for (int mt = 0; mt < 2; ++mt) {
      const int hh = h0 + mt + ky - 1;
      const bool ok = wok && ((unsigned)hh < (unsigned)H);
      const int hhc = min(max(hh, 0), H - 1);
      const ushort* pa = yt + (((size_t)b * H + hhc) * W + wwc) * C + quad * 8;
#pragma unroll
      for (int ks = 0; ks < 2; ++ks) {
        short8 v = (short8)0;
        if (ok) v = *(const short8*)(pa + ks * 32);
        afr[pb][mt][ks] = v;
      }
    }
  };

  load(0, 0);
#pragma unroll
  for (int kk = 0; kk < 9; ++kk) {
    const int pb = kk & 1;
    if (kk < 8) load(kk + 1, pb ^ 1);
#pragma unroll
    for (int ks = 0; ks < 2; ++ks)
#pragma unroll
      for (int mt = 0; mt < 2; ++mt)
#pragma unroll
        for (int nt = 0; nt < 4; ++nt)
          acc[mt][nt] = __builtin_amdgcn_mfma_f32_16x16x32_bf16(afr[pb][mt][ks], bfr[pb][ks][nt],
                                                                acc[mt][nt], 0, 0, 0);
  }

  float bias[4];
#pragma unroll
  for (int nt = 0; nt < 4; ++nt) bias[nt] = b_conv[4 * col + nt];
#pragma unroll
  for (int mt = 0; mt < 2; ++mt) {
    const int h = h0 + mt;
#pragma unroll
    for (int nt = 0; nt < 4; ++nt) {
      const int oc = 4 * col + nt; // permuted C/D col -> oc
      float4 v;
      v.x = acc[mt][nt][0] + bias[nt];
      v.y = acc[mt][nt][1] + bias[nt];
      v.z = acc[mt][nt][2] + bias[nt];
      v.w = acc[mt][nt][3] + bias[nt];
      *(float4*)&out[(((size_t)b * O + oc) * H + h) * W + w0 + quad * 4] = v;
    }
  }
}

// -------------------------------------------------------------------------
extern "C" void kernel_launch(void* const* d_in, const int* in_sizes, int n_in,
                              void* d_out, int out_size, void* d_ws, size_t ws_size,
                              hipStream_t stream) {
  const float* x = (const float*)d_in[0];
  const float* w_off = (const float*)d_in[1];
  const float* b_off = (const float*)d_in[2];
  const float* w_conv = (const float*)d_in[3];
  const float* b_conv = (const float*)d_in[4];
  float* out = (float*)d_out;

  ushort* xtb = (ushort*)d_ws;              // B*H*W*C bf16
  ushort* yt = xtb + (size_t)B * H * W * C; // B*H*W*C bf16
  ushort* wBf = yt + (size_t)B * H * W * C; // 36864 bf16
  ushort* wOf = wBf + 36864;                // 18432 bf16

  k_pre<<<dim3(2520), dim3(256), 0, stream>>>(x, xtb, w_conv, wBf, w_off, wOf);
  k_fused<<<dim3(4608), dim3(128), 0, stream>>>(xtb, wOf, b_off, wBf, b_conv, yt);
  k_conv_main_mfma<<<dim3(W / 16, H / 8, B), dim3(256), 0, stream>>>(yt, wBf, b_conv, out);
}